// Round 2
// baseline (502.669 us; speedup 1.0000x reference)
//
#include <hip/hip_runtime.h>

// Problem constants (match reference setup_inputs)
#define GH 720
#define GW 1280
#define GT 20
#define GB 8
#define NEV 500000

// Spatial tile: TY rows x TX cols, full T depth -> 20*4*64*4B = 20 KB LDS
#define TY 4
#define TX 64
#define NTY (GH / TY)            // 180
#define NTX (GW / TX)            // 20
#define NBINS (GB * NTY * NTX)   // 28800
#define SCAN_T 1024

// ---------------- Phase 1: histogram ----------------
__global__ __launch_bounds__(256) void k_hist(
    const float4* __restrict__ ev, const int* __restrict__ counts,
    unsigned* __restrict__ hist)
{
    int i = blockIdx.x * blockDim.x + threadIdx.x;
    if (i >= GB * NEV) return;
    int b = i / NEV;
    int n = i - b * NEV;
    if (n >= counts[b]) return;
    float4 e = ev[i];
    int x = min(max((int)e.x, 0), GW - 1);
    int y = min(max((int)e.y, 0), GH - 1);
    int bin = (b * NTY + (y >> 2)) * NTX + (x >> 6);
    atomicAdd(&hist[bin], 1u);
}

// ---------------- Phase 2: exclusive scan (single block) ----------------
__global__ __launch_bounds__(SCAN_T) void k_scan(
    const unsigned* __restrict__ hist,
    unsigned* __restrict__ starts, unsigned* __restrict__ cursor)
{
    __shared__ unsigned s[SCAN_T];
    int tid = threadIdx.x;
    const int chunk = (NBINS + SCAN_T - 1) / SCAN_T;  // 29
    int lo = tid * chunk;
    int hi = min(lo + chunk, NBINS);
    unsigned sum = 0;
    for (int j = lo; j < hi; j++) sum += hist[j];
    s[tid] = sum;
    __syncthreads();
    for (int off = 1; off < SCAN_T; off <<= 1) {
        unsigned v = (tid >= off) ? s[tid - off] : 0u;
        __syncthreads();
        s[tid] += v;
        __syncthreads();
    }
    unsigned base = (tid > 0) ? s[tid - 1] : 0u;
    for (int j = lo; j < hi; j++) {
        unsigned c = hist[j];
        starts[j] = base;
        cursor[j] = base;
        base += c;
    }
    if (tid == SCAN_T - 1) starts[NBINS] = s[SCAN_T - 1];
}

// ---------------- Phase 3: reorder into bin-contiguous records ----------------
__global__ __launch_bounds__(256) void k_scatter(
    const float4* __restrict__ ev, const int* __restrict__ counts,
    unsigned* __restrict__ cursor, uint2* __restrict__ sorted)
{
    int i = blockIdx.x * blockDim.x + threadIdx.x;
    if (i >= GB * NEV) return;
    int b = i / NEV;
    int n = i - b * NEV;
    if (n >= counts[b]) return;
    float4 e = ev[i];
    int x = min(max((int)e.x, 0), GW - 1);
    int y = min(max((int)e.y, 0), GH - 1);
    int bin = (b * NTY + (y >> 2)) * NTX + (x >> 6);

    float tb = e.z * (float)(GT - 1);
    int k0 = (int)floorf(tb);
    float w1 = tb - (float)k0;          // before clamping, matches reference
    int k0c = min(max(k0, 0), GT - 1);
    unsigned p = (e.w > 0.5f) ? 1u : 0u;

    unsigned word0 = (unsigned)x | ((unsigned)y << 11) | (p << 21) | ((unsigned)k0c << 22);
    unsigned pos = atomicAdd(&cursor[bin], 1u);
    sorted[pos] = make_uint2(word0, __float_as_uint(w1));
}

// ---------------- Phase 4: per-tile LDS accumulate + full-tile write ----------------
__global__ __launch_bounds__(256) void k_accum(
    const uint2* __restrict__ sorted, const unsigned* __restrict__ starts,
    float* __restrict__ out)
{
    __shared__ float tile[GT * TY * TX];     // 5120 floats = 20 KB
    int bin = blockIdx.x;
    int tid = threadIdx.x;

    for (int j = tid; j < GT * TY * TX; j += 256) tile[j] = 0.0f;
    __syncthreads();

    unsigned s0 = starts[bin], s1 = starts[bin + 1];
    for (unsigned idx = s0 + tid; idx < s1; idx += 256) {
        uint2 r = sorted[idx];
        int x  = r.x & 2047;
        int y  = (r.x >> 11) & 1023;
        int p  = (r.x >> 21) & 1;
        int k0 = (r.x >> 22) & 31;
        float w1 = __uint_as_float(r.y);
        float w0 = 1.0f - w1;
        float pol = p ? 1.0f : -1.0f;
        int k1 = min(k0 + 1, GT - 1);
        int yy = y & (TY - 1);
        int xx = x & (TX - 1);
        atomicAdd(&tile[(k0 * TY + yy) * TX + xx], pol * w0);
        atomicAdd(&tile[(k1 * TY + yy) * TX + xx], pol * w1);
    }
    __syncthreads();

    // decompose bin -> (b, ty, tx)
    int tx = bin % NTX;
    int rem = bin / NTX;
    int ty = rem % NTY;
    int b  = rem / NTY;
    int y0 = ty * TY;
    int x0 = tx * TX;

    const float4* t4 = (const float4*)tile;
    float4* o4 = (float4*)out;
    // 1280 float4 per tile; 16 float4 per (k,yy) row of 64 floats
    for (int j = tid; j < GT * TY * (TX / 4); j += 256) {
        int row = j >> 4;                 // k*TY + yy
        int col = j & 15;
        int k  = row >> 2;                // /TY
        int yy = row & (TY - 1);
        int off = ((b * GT + k) * GH + (y0 + yy)) * (GW / 4) + (x0 >> 2) + col;
        o4[off] = t4[j];
    }
}

// ---------------- Fallback (round-1 path) ----------------
__global__ __launch_bounds__(256) void ev2voxel_scatter(
    const float4* __restrict__ ev, const int* __restrict__ counts,
    float* __restrict__ out)
{
    int i = blockIdx.x * blockDim.x + threadIdx.x;
    if (i >= GB * NEV) return;
    int b = i / NEV;
    int n = i - b * NEV;
    if (n >= counts[b]) return;
    float4 e = ev[i];
    int x = min(max((int)e.x, 0), GW - 1);
    int y = min(max((int)e.y, 0), GH - 1);
    float pol = e.w * 2.0f - 1.0f;
    float tb = e.z * (float)(GT - 1);
    int k0 = (int)floorf(tb);
    float w1 = tb - (float)k0;
    float w0 = 1.0f - w1;
    int k0c = min(max(k0, 0), GT - 1);
    int k1c = min(max(k0 + 1, 0), GT - 1);
    int rowbase = (b * GT) * GH;
    atomicAdd(&out[(rowbase + k0c * GH + y) * GW + x], pol * w0);
    atomicAdd(&out[(rowbase + k1c * GH + y) * GW + x], pol * w1);
}

extern "C" void kernel_launch(void* const* d_in, const int* in_sizes, int n_in,
                              void* d_out, int out_size, void* d_ws, size_t ws_size,
                              hipStream_t stream) {
    const float4* ev = (const float4*)d_in[0];   // (B, N, 4) fp32
    const int* counts = (const int*)d_in[1];     // (B,) int
    float* out = (float*)d_out;                  // (B, T, H, W) fp32

    // workspace layout (uint32 units):
    //   hist  [NBINS]
    //   starts[NBINS+1]
    //   cursor[NBINS]
    //   (pad to 8B) sorted[GB*NEV] as uint2
    const size_t hist_off   = 0;
    const size_t starts_off = NBINS;
    const size_t cursor_off = starts_off + NBINS + 1;
    size_t sorted_off = cursor_off + NBINS;
    if (sorted_off & 1) sorted_off++;            // 8B align
    const size_t need_bytes = sorted_off * 4 + (size_t)GB * NEV * 8;

    const int total = GB * NEV;
    const int block = 256;
    const int grid = (total + block - 1) / block;

    if (ws_size < need_bytes) {
        // fallback: direct atomic scatter
        hipMemsetAsync(out, 0, (size_t)out_size * sizeof(float), stream);
        ev2voxel_scatter<<<grid, block, 0, stream>>>(ev, counts, out);
        return;
    }

    unsigned* ws = (unsigned*)d_ws;
    unsigned* hist   = ws + hist_off;
    unsigned* starts = ws + starts_off;
    unsigned* cursor = ws + cursor_off;
    uint2*    sorted = (uint2*)(ws + sorted_off);

    hipMemsetAsync(hist, 0, NBINS * sizeof(unsigned), stream);
    k_hist<<<grid, block, 0, stream>>>(ev, counts, hist);
    k_scan<<<1, SCAN_T, 0, stream>>>(hist, starts, cursor);
    k_scatter<<<grid, block, 0, stream>>>(ev, counts, cursor, sorted);
    k_accum<<<NBINS, 256, 0, stream>>>(sorted, starts, out);
}

// Round 3
// 498.118 us; speedup vs baseline: 1.0091x; 1.0091x over previous
//
#include <hip/hip_runtime.h>

// Problem constants (match reference setup_inputs)
#define GH 720
#define GW 1280
#define GT 20
#define GB 8
#define NEV 500000

// Spatial tile: TY rows x TX cols, full T depth -> 20*4*64*4B = 20 KB LDS
#define TY 4
#define TX 64
#define NTY (GH / TY)            // 180
#define NTX (GW / TX)            // 20
#define NBINS (GB * NTY * NTX)   // 28800
#define SCAN_T 1024

// ---------------- Phase 0: zero the histogram (graph-captured memset of
// small buffers is pathologically slow: 112.5KB fill measured at 351us) ----
__global__ __launch_bounds__(256) void k_zero(unsigned* __restrict__ hist)
{
    int i = blockIdx.x * blockDim.x + threadIdx.x;
    if (i < NBINS) hist[i] = 0u;
}

// ---------------- Phase 1: histogram ----------------
__global__ __launch_bounds__(256) void k_hist(
    const float4* __restrict__ ev, const int* __restrict__ counts,
    unsigned* __restrict__ hist)
{
    int i = blockIdx.x * blockDim.x + threadIdx.x;
    if (i >= GB * NEV) return;
    int b = i / NEV;
    int n = i - b * NEV;
    if (n >= counts[b]) return;
    float4 e = ev[i];
    int x = min(max((int)e.x, 0), GW - 1);
    int y = min(max((int)e.y, 0), GH - 1);
    int bin = (b * NTY + (y >> 2)) * NTX + (x >> 6);
    atomicAdd(&hist[bin], 1u);
}

// ---------------- Phase 2: exclusive scan (single block) ----------------
__global__ __launch_bounds__(SCAN_T) void k_scan(
    const unsigned* __restrict__ hist,
    unsigned* __restrict__ starts, unsigned* __restrict__ cursor)
{
    __shared__ unsigned s[SCAN_T];
    int tid = threadIdx.x;
    const int chunk = (NBINS + SCAN_T - 1) / SCAN_T;  // 29
    int lo = tid * chunk;
    int hi = min(lo + chunk, NBINS);
    unsigned sum = 0;
    for (int j = lo; j < hi; j++) sum += hist[j];
    s[tid] = sum;
    __syncthreads();
    for (int off = 1; off < SCAN_T; off <<= 1) {
        unsigned v = (tid >= off) ? s[tid - off] : 0u;
        __syncthreads();
        s[tid] += v;
        __syncthreads();
    }
    unsigned base = (tid > 0) ? s[tid - 1] : 0u;
    for (int j = lo; j < hi; j++) {
        unsigned c = hist[j];
        starts[j] = base;
        cursor[j] = base;
        base += c;
    }
    if (tid == SCAN_T - 1) starts[NBINS] = s[SCAN_T - 1];
}

// ---------------- Phase 3: reorder into bin-contiguous records ----------------
__global__ __launch_bounds__(256) void k_scatter(
    const float4* __restrict__ ev, const int* __restrict__ counts,
    unsigned* __restrict__ cursor, uint2* __restrict__ sorted)
{
    int i = blockIdx.x * blockDim.x + threadIdx.x;
    if (i >= GB * NEV) return;
    int b = i / NEV;
    int n = i - b * NEV;
    if (n >= counts[b]) return;
    float4 e = ev[i];
    int x = min(max((int)e.x, 0), GW - 1);
    int y = min(max((int)e.y, 0), GH - 1);
    int bin = (b * NTY + (y >> 2)) * NTX + (x >> 6);

    float tb = e.z * (float)(GT - 1);
    int k0 = (int)floorf(tb);
    float w1 = tb - (float)k0;          // before clamping, matches reference
    int k0c = min(max(k0, 0), GT - 1);
    unsigned p = (e.w > 0.5f) ? 1u : 0u;

    unsigned word0 = (unsigned)x | ((unsigned)y << 11) | (p << 21) | ((unsigned)k0c << 22);
    unsigned pos = atomicAdd(&cursor[bin], 1u);
    sorted[pos] = make_uint2(word0, __float_as_uint(w1));
}

// ---------------- Phase 4: per-tile LDS accumulate + full-tile write ----------------
__global__ __launch_bounds__(256) void k_accum(
    const uint2* __restrict__ sorted, const unsigned* __restrict__ starts,
    float* __restrict__ out)
{
    __shared__ float tile[GT * TY * TX];     // 5120 floats = 20 KB
    int bin = blockIdx.x;
    int tid = threadIdx.x;

    for (int j = tid; j < GT * TY * TX; j += 256) tile[j] = 0.0f;
    __syncthreads();

    unsigned s0 = starts[bin], s1 = starts[bin + 1];
    for (unsigned idx = s0 + tid; idx < s1; idx += 256) {
        uint2 r = sorted[idx];
        int x  = r.x & 2047;
        int y  = (r.x >> 11) & 1023;
        int p  = (r.x >> 21) & 1;
        int k0 = (r.x >> 22) & 31;
        float w1 = __uint_as_float(r.y);
        float w0 = 1.0f - w1;
        float pol = p ? 1.0f : -1.0f;
        int k1 = min(k0 + 1, GT - 1);
        int yy = y & (TY - 1);
        int xx = x & (TX - 1);
        atomicAdd(&tile[(k0 * TY + yy) * TX + xx], pol * w0);
        atomicAdd(&tile[(k1 * TY + yy) * TX + xx], pol * w1);
    }
    __syncthreads();

    // decompose bin -> (b, ty, tx)
    int tx = bin % NTX;
    int rem = bin / NTX;
    int ty = rem % NTY;
    int b  = rem / NTY;
    int y0 = ty * TY;
    int x0 = tx * TX;

    const float4* t4 = (const float4*)tile;
    float4* o4 = (float4*)out;
    // 1280 float4 per tile; 16 float4 per (k,yy) row of 64 floats
    for (int j = tid; j < GT * TY * (TX / 4); j += 256) {
        int row = j >> 4;                 // k*TY + yy
        int col = j & 15;
        int k  = row >> 2;                // /TY
        int yy = row & (TY - 1);
        int off = ((b * GT + k) * GH + (y0 + yy)) * (GW / 4) + (x0 >> 2) + col;
        o4[off] = t4[j];
    }
}

// ---------------- Fallback (round-1 path) ----------------
__global__ __launch_bounds__(256) void ev2voxel_scatter(
    const float4* __restrict__ ev, const int* __restrict__ counts,
    float* __restrict__ out)
{
    int i = blockIdx.x * blockDim.x + threadIdx.x;
    if (i >= GB * NEV) return;
    int b = i / NEV;
    int n = i - b * NEV;
    if (n >= counts[b]) return;
    float4 e = ev[i];
    int x = min(max((int)e.x, 0), GW - 1);
    int y = min(max((int)e.y, 0), GH - 1);
    float pol = e.w * 2.0f - 1.0f;
    float tb = e.z * (float)(GT - 1);
    int k0 = (int)floorf(tb);
    float w1 = tb - (float)k0;
    float w0 = 1.0f - w1;
    int k0c = min(max(k0, 0), GT - 1);
    int k1c = min(max(k0 + 1, 0), GT - 1);
    int rowbase = (b * GT) * GH;
    atomicAdd(&out[(rowbase + k0c * GH + y) * GW + x], pol * w0);
    atomicAdd(&out[(rowbase + k1c * GH + y) * GW + x], pol * w1);
}

extern "C" void kernel_launch(void* const* d_in, const int* in_sizes, int n_in,
                              void* d_out, int out_size, void* d_ws, size_t ws_size,
                              hipStream_t stream) {
    const float4* ev = (const float4*)d_in[0];   // (B, N, 4) fp32
    const int* counts = (const int*)d_in[1];     // (B,) int
    float* out = (float*)d_out;                  // (B, T, H, W) fp32

    // workspace layout (uint32 units):
    //   hist  [NBINS]
    //   starts[NBINS+1]
    //   cursor[NBINS]
    //   (pad to 8B) sorted[GB*NEV] as uint2
    const size_t hist_off   = 0;
    const size_t starts_off = NBINS;
    const size_t cursor_off = starts_off + NBINS + 1;
    size_t sorted_off = cursor_off + NBINS;
    if (sorted_off & 1) sorted_off++;            // 8B align
    const size_t need_bytes = sorted_off * 4 + (size_t)GB * NEV * 8;

    const int total = GB * NEV;
    const int block = 256;
    const int grid = (total + block - 1) / block;

    if (ws_size < need_bytes) {
        // fallback: direct atomic scatter
        hipMemsetAsync(out, 0, (size_t)out_size * sizeof(float), stream);
        ev2voxel_scatter<<<grid, block, 0, stream>>>(ev, counts, out);
        return;
    }

    unsigned* ws = (unsigned*)d_ws;
    unsigned* hist   = ws + hist_off;
    unsigned* starts = ws + starts_off;
    unsigned* cursor = ws + cursor_off;
    uint2*    sorted = (uint2*)(ws + sorted_off);

    k_zero<<<(NBINS + 255) / 256, 256, 0, stream>>>(hist);
    k_hist<<<grid, block, 0, stream>>>(ev, counts, hist);
    k_scan<<<1, SCAN_T, 0, stream>>>(hist, starts, cursor);
    k_scatter<<<grid, block, 0, stream>>>(ev, counts, cursor, sorted);
    k_accum<<<NBINS, 256, 0, stream>>>(sorted, starts, out);
}

// Round 5
// 305.207 us; speedup vs baseline: 1.6470x; 1.6321x over previous
//
#include <hip/hip_runtime.h>

// Problem constants (match reference setup_inputs)
#define GH 720
#define GW 1280
#define GT 20
#define GB 8
#define NEV 500000

// Spatial tile: TY rows x TX cols, full T depth -> 20*4*64*4B = 20 KB LDS
#define TY 4
#define TX 64
#define NTY (GH / TY)            // 180
#define NTX (GW / TX)            // 20
#define NBINS (GB * NTY * NTX)   // 28800
#define CAP 512                  // bucket capacity (avg load ~139, max ~200)
#define OVF_CAP (1u << 20)

typedef float vfloat4 __attribute__((ext_vector_type(4)));   // clang vector type for nontemporal builtins

// ---------------- Phase 0: zero bin counters + overflow counter ----------------
__global__ __launch_bounds__(256) void k_zero(unsigned* __restrict__ cnt)
{
    int i = blockIdx.x * blockDim.x + threadIdx.x;
    if (i < NBINS + 1) cnt[i] = 0u;   // cnt[NBINS] is ovfcnt
}

// ---------------- Phase 1: single-pass bucket scatter ----------------
// record: word0 = x | y<<11 | p<<21 | k0c<<22 | b<<27 ; word1 = w1 bits
__global__ __launch_bounds__(256) void k_bucket(
    const float4* __restrict__ ev, const int* __restrict__ counts,
    unsigned* __restrict__ cnt, uint2* __restrict__ buckets,
    uint2* __restrict__ ovf)
{
    int i = blockIdx.x * blockDim.x + threadIdx.x;
    if (i >= GB * NEV) return;
    int b = i / NEV;                    // constant divisor -> magic-mul
    int n = i - b * NEV;
    if (n >= counts[b]) return;

    float4 e = ev[i];
    int x = min(max((int)e.x, 0), GW - 1);
    int y = min(max((int)e.y, 0), GH - 1);
    int bin = (b * NTY + (y >> 2)) * NTX + (x >> 6);

    float tb = e.z * (float)(GT - 1);
    int k0 = (int)floorf(tb);
    float w1 = tb - (float)k0;          // before clamping, matches reference
    int k0c = min(max(k0, 0), GT - 1);
    unsigned p = (e.w > 0.5f) ? 1u : 0u;

    unsigned word0 = (unsigned)x | ((unsigned)y << 11) | (p << 21)
                   | ((unsigned)k0c << 22) | ((unsigned)b << 27);
    uint2 rec = make_uint2(word0, __float_as_uint(w1));

    unsigned pos = atomicAdd(&cnt[bin], 1u);
    if (pos < CAP) {
        buckets[(size_t)bin * CAP + pos] = rec;
    } else {
        unsigned o = atomicAdd(&cnt[NBINS], 1u);
        if (o < OVF_CAP) ovf[o] = rec;
    }
}

// ---------------- Phase 2: per-tile LDS accumulate + full-tile write ----------------
__global__ __launch_bounds__(256) void k_accum(
    const uint2* __restrict__ buckets, const unsigned* __restrict__ cnt,
    float* __restrict__ out)
{
    __shared__ float tile[GT * TY * TX];     // 5120 floats = 20 KB
    int bin = blockIdx.x;
    int tid = threadIdx.x;

    vfloat4* t4z = (vfloat4*)tile;
    for (int j = tid; j < GT * TY * (TX / 4); j += 256) t4z[j] = (vfloat4){0.f, 0.f, 0.f, 0.f};
    __syncthreads();

    unsigned m = min(cnt[bin], (unsigned)CAP);
    const uint2* bp = buckets + (size_t)bin * CAP;
    for (unsigned idx = tid; idx < m; idx += 256) {
        uint2 r = bp[idx];
        int x  = r.x & 2047;
        int y  = (r.x >> 11) & 1023;
        int p  = (r.x >> 21) & 1;
        int k0 = (r.x >> 22) & 31;
        float w1 = __uint_as_float(r.y);
        float w0 = 1.0f - w1;
        float pol = p ? 1.0f : -1.0f;
        int k1 = min(k0 + 1, GT - 1);
        int yy = y & (TY - 1);
        int xx = x & (TX - 1);
        atomicAdd(&tile[(k0 * TY + yy) * TX + xx], pol * w0);
        atomicAdd(&tile[(k1 * TY + yy) * TX + xx], pol * w1);
    }
    __syncthreads();

    // decompose bin -> (b, ty, tx)
    int tx = bin % NTX;
    int rem = bin / NTX;
    int ty = rem % NTY;
    int b  = rem / NTY;
    int y0 = ty * TY;
    int x0 = tx * TX;

    const vfloat4* t4 = (const vfloat4*)tile;
    vfloat4* o4 = (vfloat4*)out;
    // 1280 float4 per tile; 16 float4 per (k,yy) row of 64 floats
    for (int j = tid; j < GT * TY * (TX / 4); j += 256) {
        int row = j >> 4;                 // k*TY + yy
        int col = j & 15;
        int k  = row >> 2;                // /TY
        int yy = row & (TY - 1);
        int off = ((b * GT + k) * GH + (y0 + yy)) * (GW / 4) + (x0 >> 2) + col;
        __builtin_nontemporal_store(t4[j], &o4[off]);   // write-once, skip L2 pollution
    }
}

// ---------------- Phase 3: replay overflow events (normally zero) ----------------
__global__ __launch_bounds__(256) void k_overflow(
    const uint2* __restrict__ ovf, const unsigned* __restrict__ cnt,
    float* __restrict__ out)
{
    unsigned n = min(cnt[NBINS], OVF_CAP);
    for (unsigned i = blockIdx.x * blockDim.x + threadIdx.x; i < n;
         i += gridDim.x * blockDim.x) {
        uint2 r = ovf[i];
        int x  = r.x & 2047;
        int y  = (r.x >> 11) & 1023;
        int p  = (r.x >> 21) & 1;
        int k0 = (r.x >> 22) & 31;
        int b  = (r.x >> 27) & 7;
        float w1 = __uint_as_float(r.y);
        float w0 = 1.0f - w1;
        float pol = p ? 1.0f : -1.0f;
        int k1 = min(k0 + 1, GT - 1);
        atomicAdd(&out[((b * GT + k0) * GH + y) * GW + x], pol * w0);
        atomicAdd(&out[((b * GT + k1) * GH + y) * GW + x], pol * w1);
    }
}

// ---------------- Fallback (round-1 path) ----------------
__global__ __launch_bounds__(256) void ev2voxel_scatter(
    const float4* __restrict__ ev, const int* __restrict__ counts,
    float* __restrict__ out)
{
    int i = blockIdx.x * blockDim.x + threadIdx.x;
    if (i >= GB * NEV) return;
    int b = i / NEV;
    int n = i - b * NEV;
    if (n >= counts[b]) return;
    float4 e = ev[i];
    int x = min(max((int)e.x, 0), GW - 1);
    int y = min(max((int)e.y, 0), GH - 1);
    float pol = e.w * 2.0f - 1.0f;
    float tb = e.z * (float)(GT - 1);
    int k0 = (int)floorf(tb);
    float w1 = tb - (float)k0;
    float w0 = 1.0f - w1;
    int k0c = min(max(k0, 0), GT - 1);
    int k1c = min(max(k0 + 1, 0), GT - 1);
    int rowbase = (b * GT) * GH;
    atomicAdd(&out[(rowbase + k0c * GH + y) * GW + x], pol * w0);
    atomicAdd(&out[(rowbase + k1c * GH + y) * GW + x], pol * w1);
}

extern "C" void kernel_launch(void* const* d_in, const int* in_sizes, int n_in,
                              void* d_out, int out_size, void* d_ws, size_t ws_size,
                              hipStream_t stream) {
    const float4* ev = (const float4*)d_in[0];   // (B, N, 4) fp32
    const int* counts = (const int*)d_in[1];     // (B,) int
    float* out = (float*)d_out;                  // (B, T, H, W) fp32

    // workspace layout (u32 units): cnt[NBINS] + ovfcnt[1], pad to 8B,
    // buckets[NBINS*CAP] uint2, ovf[OVF_CAP] uint2
    size_t bucket_off = NBINS + 1;
    if (bucket_off & 1) bucket_off++;
    const size_t ovf_off = bucket_off + (size_t)NBINS * CAP * 2;   // in u32
    const size_t need_bytes = (ovf_off + (size_t)OVF_CAP * 2) * 4;

    const int total = GB * NEV;
    const int block = 256;
    const int grid = (total + block - 1) / block;

    if (ws_size < need_bytes) {
        (void)hipMemsetAsync(out, 0, (size_t)out_size * sizeof(float), stream);
        ev2voxel_scatter<<<grid, block, 0, stream>>>(ev, counts, out);
        return;
    }

    unsigned* ws = (unsigned*)d_ws;
    unsigned* cnt = ws;                              // NBINS + 1 (ovf counter)
    uint2* buckets = (uint2*)(ws + bucket_off);
    uint2* ovf     = (uint2*)(ws + ovf_off);

    k_zero<<<(NBINS + 1 + 255) / 256, 256, 0, stream>>>(cnt);
    k_bucket<<<grid, block, 0, stream>>>(ev, counts, cnt, buckets, ovf);
    k_accum<<<NBINS, 256, 0, stream>>>(buckets, cnt, out);
    k_overflow<<<64, 256, 0, stream>>>(ovf, cnt, out);
}